// Round 13
// baseline (2018.942 us; speedup 1.0000x reference)
//
#include <hip/hip_runtime.h>

// B=4, N=M=4096, D=128.
// d_out (floats): match_mask [4*4096*4096] | pairs [16384] (as float) | top_dists [16384]
// ws fast path:
//   bytes [0, 131072):        x2 [16384] f32 | y2 [16384] f32
//   bytes [131072, 25296896): planes, 6 x PS elems bf16 (x:h,m,l then y:h,m,l)
//     chunk layout: [b(4)][kh(2)][tile(32)] -> 8192-elem (16 KiB) chunk
//     within chunk: [rb(8)][kc(2)][lane(64)][e(8)], value = in[b][tile*128+rb*16+(l&15)][kh*64+kc*32+(l>>4)*8+e]
//   then pv [16384*2] f32 | pi [16384*2] i32
// Products: hh, hm, mh, mm, hl, lh. Per kh: B=h -> A{h,m,l}; B=m -> A{h,m}; B=l -> A{h}.
// Round-13: 1024-thread blocks (16 waves = 4/SIMD, 2x TLP of the 200us plateau).
// 4x4 wave grid of 32x32 tiles -> tiny per-thread state (no spills at the hard
// 128-VGPR cap). Same 2-phase/nt counted-wait skeleton; waits nA=6, nB=24.

typedef float  f32x4  __attribute__((ext_vector_type(4)));
typedef short  bf16x8 __attribute__((ext_vector_type(8)));

#define PS ((size_t)2097152)

#define WAITVM_(N) asm volatile("s_waitcnt vmcnt(" #N ")" ::: "memory")
#define WAITVM(N)  WAITVM_(N)
#define BAR        __builtin_amdgcn_s_barrier()
#define FENCE      asm volatile("" ::: "memory")

__device__ __forceinline__ unsigned short f2bf(float x) {
    unsigned u = __float_as_uint(x);
    u += 0x7FFFu + ((u >> 16) & 1u);
    return (unsigned short)(u >> 16);
}
__device__ __forceinline__ float bf2f(unsigned short s) {
    return __uint_as_float(((unsigned)s) << 16);
}
__device__ __forceinline__ void gload_lds16(const void* g, void* l) {
    __builtin_amdgcn_global_load_lds(
        (const __attribute__((address_space(1))) void*)g,
        (__attribute__((address_space(3))) void*)l, 16, 0, 0);
}

// ---- split f32 -> 3 bf16 planes (fragment order) + fused row sum-of-squares ----
__global__ __launch_bounds__(256) void k_prep(const float* __restrict__ xd,
                                              const float* __restrict__ yd,
                                              unsigned short* __restrict__ pl,
                                              float* __restrict__ ws) {
    __shared__ float sm[4][16];
    int bid  = blockIdx.x;            // 0..2047
    int i    = bid >> 10;
    int b    = (bid >> 8) & 3;
    int rblk = bid & 255;
    int tid  = threadIdx.x;
    int kb   = tid >> 6;
    int l    = tid & 63;
    int r    = rblk * 16 + (l & 15);
    int k0   = kb * 32 + ((l >> 4) & 3) * 8;
    const float* src = (i ? yd : xd) + ((size_t)(b * 4096 + r) * 128 + k0);
    float v[8];
    *reinterpret_cast<float4*>(v)     = *reinterpret_cast<const float4*>(src);
    *reinterpret_cast<float4*>(v + 4) = *reinterpret_cast<const float4*>(src + 4);
    bf16x8 hv, mv, lv;
    float s = 0.f;
    #pragma unroll
    for (int e = 0; e < 8; ++e) {
        float x = v[e];
        s = fmaf(x, x, s);
        unsigned short h  = f2bf(x);
        float r1 = x - bf2f(h);
        unsigned short m  = f2bf(r1);
        float r2 = r1 - bf2f(m);
        unsigned short lo = f2bf(r2);
        hv[e] = (short)h; mv[e] = (short)m; lv[e] = (short)lo;
    }
    int rt = rblk >> 3, rb = rblk & 7, kh = kb >> 1, kc = kb & 1;
    size_t base = ((((size_t)((b * 2 + kh) * 32 + rt)) * 8 + rb) * 2 + kc) * 512 + (size_t)l * 8;
    unsigned short* dst = pl + (size_t)(i * 3) * PS;
    *reinterpret_cast<bf16x8*>(dst + base)          = hv;
    *reinterpret_cast<bf16x8*>(dst + base + PS)     = mv;
    *reinterpret_cast<bf16x8*>(dst + base + 2 * PS) = lv;
    s += __shfl_xor(s, 16);
    s += __shfl_xor(s, 32);
    if (l < 16) sm[kb][l] = s;
    __syncthreads();
    if (tid < 16) {
        float t = sm[0][tid] + sm[1][tid] + sm[2][tid] + sm[3][tid];
        ws[(i ? 16384 : 0) + b * 4096 + rblk * 16 + tid] = t;
    }
}

// ---- main: 16-wave blocks (4 waves/SIMD), full-A LDS, 2-phase/nt pipeline ----
__global__ __launch_bounds__(1024) void k_gemm(const float* __restrict__ mask,
                                               const float* __restrict__ ws,
                                               const unsigned short* __restrict__ pl,
                                               float* __restrict__ out,
                                               float* __restrict__ pv,
                                               int* __restrict__ pi) {
    __shared__ __align__(16) unsigned short Ab[2][3][8192];  // 96 KiB: A h,m,l per kh
    __shared__ __align__(16) unsigned short Bp[2][2][8192];  // 64 KiB: [kh-slot][plane h,m]

    const int bid = blockIdx.x;        // 256 blocks = 1/CU
    const int xcd = bid & 7;
    const int b   = xcd >> 1;          // batch pinned per XCD pair
    const int ch  = xcd & 1;           // col half (2048 cols)
    const int rt  = bid >> 3;          // 128-row tile 0..31
    const int tid = threadIdx.x;
    const int w   = tid >> 6, l = tid & 63;
    const int wr  = w >> 2, wc = w & 3;     // 4x4 waves: 32 rows x 32 cols each
    const int lg4 = (l >> 4) & 3, l15 = l & 15;
    const int g0  = b * 4096 + rt * 128;

    float x2r[8];
    #pragma unroll
    for (int mi = 0; mi < 2; ++mi)
        #pragma unroll
        for (int rg = 0; rg < 4; ++rg)
            x2r[mi * 4 + rg] = ws[g0 + wr * 32 + mi * 16 + lg4 * 4 + rg];

    const float* mrow = mask + (size_t)(g0 + wr * 32 + lg4 * 4) * 4096
                        + ch * 2048 + wc * 32 + l15;
    const float* y2b  = ws + 16384 + b * 4096 + ch * 2048 + wc * 32 + l15;

#define STAGE2(NTT, KH, SLOT) do {                                                \
    _Pragma("unroll") for (int bp_ = 0; bp_ < 2; ++bp_) {                         \
        const unsigned short* Bc_ = pl + (size_t)(3 + bp_) * PS                   \
            + (((size_t)((b * 2 + (KH)) * 32 + ch * 16 + (NTT))) << 13);          \
        gload_lds16((const char*)Bc_ + w * 1024 + l * 16,                         \
                    (char*)(&Bp[SLOT][bp_][0]) + w * 1024);                       \
    }                                                                             \
} while (0)

#define BLLOAD(DST, NTT, KH) do {                                                 \
    const unsigned short* Bc_ = pl + (size_t)5 * PS                               \
        + (((size_t)((b * 2 + (KH)) * 32 + ch * 16 + (NTT))) << 13);              \
    _Pragma("unroll") for (int ni = 0; ni < 2; ++ni)                              \
    _Pragma("unroll") for (int kc = 0; kc < 2; ++kc)                              \
        DST[ni][kc] = *reinterpret_cast<const bf16x8*>(                           \
            Bc_ + (((wc * 2 + ni) * 2 + kc) << 9) + l * 8);                       \
} while (0)

#define MLOAD16(NT) do {                                                          \
    _Pragma("unroll") for (int K = 0; K < 16; ++K) {                              \
        const int mi_ = K >> 3, rg_ = (K >> 1) & 3, ni_ = K & 1;                  \
        pm[mi_ * 8 + rg_ * 2 + ni_] =                                             \
            mrow[(size_t)(mi_ * 16 + rg_) * 4096 + (NT) * 128 + ni_ * 16];        \
    }                                                                             \
    yv[0] = y2b[(NT) * 128];                                                      \
    yv[1] = y2b[(NT) * 128 + 16];                                                 \
} while (0)

#define ZST(NT, I) do {                                                           \
    const f32x4 z_ = (f32x4){0.f, 0.f, 0.f, 0.f};                                 \
    const int i_ = (I) * 1024 + tid;                                              \
    *reinterpret_cast<f32x4*>(out + (size_t)(g0 + (i_ >> 5)) * 4096               \
        + ch * 2048 + (NT) * 128 + ((i_ & 31) << 2)) = z_;                        \
} while (0)

// B h,m from LDS slot, B-l from BL regs; A h,m,l from LDS. 48 MFMA/phase.
#define COMPUTE(KH, SLOT, BL) do {                                                \
    __builtin_amdgcn_s_setprio(1);                                                \
    _Pragma("unroll") for (int mi = 0; mi < 2; ++mi)                              \
    _Pragma("unroll") for (int kc = 0; kc < 2; ++kc) {                            \
        const int fa = (((wr * 2 + mi) * 2 + kc) << 9) + l * 8;                   \
        bf16x8 Ah_ = *reinterpret_cast<const bf16x8*>(&Ab[KH][0][fa]);            \
        bf16x8 Am_ = *reinterpret_cast<const bf16x8*>(&Ab[KH][1][fa]);            \
        bf16x8 Al_ = *reinterpret_cast<const bf16x8*>(&Ab[KH][2][fa]);            \
        _Pragma("unroll") for (int ni = 0; ni < 2; ++ni) {                        \
            const int fb = (((wc * 2 + ni) * 2 + kc) << 9) + l * 8;               \
            bf16x8 Bh_ = *reinterpret_cast<const bf16x8*>(&Bp[SLOT][0][fb]);      \
            bf16x8 Bm_ = *reinterpret_cast<const bf16x8*>(&Bp[SLOT][1][fb]);      \
            f32x4 c_ = acc[mi][ni];                                               \
            c_ = __builtin_amdgcn_mfma_f32_16x16x32_bf16(Ah_, Bh_, c_, 0, 0, 0);  \
            c_ = __builtin_amdgcn_mfma_f32_16x16x32_bf16(Am_, Bh_, c_, 0, 0, 0);  \
            c_ = __builtin_amdgcn_mfma_f32_16x16x32_bf16(Al_, Bh_, c_, 0, 0, 0);  \
            c_ = __builtin_amdgcn_mfma_f32_16x16x32_bf16(Ah_, Bm_, c_, 0, 0, 0);  \
            c_ = __builtin_amdgcn_mfma_f32_16x16x32_bf16(Am_, Bm_, c_, 0, 0, 0);  \
            c_ = __builtin_amdgcn_mfma_f32_16x16x32_bf16(Ah_, BL[ni][kc], c_, 0, 0, 0); \
            acc[mi][ni] = c_;                                                     \
        }                                                                         \
    }                                                                             \
    __builtin_amdgcn_s_setprio(0);                                                \
} while (0)

#define EPILOGUE(NT) do {                                                         \
    _Pragma("unroll") for (int ni = 0; ni < 2; ++ni) {                            \
        const int c = ch * 2048 + (NT) * 128 + wc * 32 + ni * 16 + l15;           \
        _Pragma("unroll") for (int mi = 0; mi < 2; ++mi)                          \
        _Pragma("unroll") for (int rg = 0; rg < 4; ++rg) {                        \
            float d2 = fmaf(acc[mi][ni][rg], -2.0f, x2r[mi * 4 + rg]) + yv[ni];   \
            float d  = sqrtf(fmaxf(d2, 0.0f)) * pm[mi * 8 + rg * 2 + ni];         \
            double pk = __hiloint2double(__float_as_int(d), c);                   \
            bv[mi * 4 + rg] = fmin(bv[mi * 4 + rg], pk);                          \
        }                                                                         \
    }                                                                             \
} while (0)

    // ---- prologue: A (6 chunks) -> LDS; B nt0 kh0 -> slot0; BlA; masks nt0 ----
    #pragma unroll
    for (int kh = 0; kh < 2; ++kh)
        #pragma unroll
        for (int ap = 0; ap < 3; ++ap) {
            const unsigned short* Ac = pl + (size_t)ap * PS
                + (((size_t)((b * 2 + kh) * 32 + rt)) << 13);
            gload_lds16((const char*)Ac + w * 1024 + l * 16,
                        (char*)(&Ab[kh][ap][0]) + w * 1024);
        }

    bf16x8 BlA[2][2], BlB[2][2];
    float pm[16], yv[2];

    STAGE2(0, 0, 0);
    BLLOAD(BlA, 0, 0);
    MLOAD16(0);
    WAITVM(0);
    BAR;

    const double INITD = __hiloint2double(0x7f7fffff, 0);
    double bv[8];
    #pragma unroll
    for (int q = 0; q < 8; ++q) bv[q] = INITD;

    f32x4 acc[2][2];

    #pragma unroll 1
    for (int nt = 0; nt < 16; ++nt) {
        const int ntn = (nt < 15) ? nt + 1 : 15;

        // ---- Phase A: compute kh0 (slot0 + BlA); stage kh1 -> slot1 + BlB ----
        WAITVM(6); BAR;                 // retire prev B stage; leave BlA'(4)+ZB(2)
        #pragma unroll
        for (int mi = 0; mi < 2; ++mi)
            #pragma unroll
            for (int ni = 0; ni < 2; ++ni) acc[mi][ni] = (f32x4){0.f, 0.f, 0.f, 0.f};
        STAGE2(nt, 1, 1);
        BLLOAD(BlB, nt, 1);
        if (nt > 0) MLOAD16(nt);        // nt0's masks loaded in prologue
        FENCE;
        ZST(nt, 0); ZST(nt, 1);
        COMPUTE(0, 0, BlA);

        // ---- Phase B: compute kh1 (slot1 + BlB); stage next kh0 -> slot0 ----
        WAITVM(24); BAR;                // retire A's stage; leave BlB+masks+ZA
        STAGE2(ntn, 0, 0);
        BLLOAD(BlA, ntn, 0);
        FENCE;
        ZST(nt, 2); ZST(nt, 3);
        COMPUTE(1, 1, BlB);
        EPILOGUE(nt);                   // pm/yv retired by compiler auto-waits
    }
#undef STAGE2
#undef BLLOAD
#undef MLOAD16
#undef ZST
#undef COMPUTE
#undef EPILOGUE

    WAITVM(0);

    // ---- reduce across 16 col-lanes (packed min), then 4 col-waves via LDS ----
    #pragma unroll
    for (int off = 1; off < 16; off <<= 1) {
        #pragma unroll
        for (int q = 0; q < 8; ++q)
            bv[q] = fmin(bv[q], __shfl_xor(bv[q], off));
    }
    __syncthreads();                    // B LDS free; overlay candidates
    double* cd = reinterpret_cast<double*>(&Bp[0][0][0]);   // [128][4]
    if (l15 == 0) {
        #pragma unroll
        for (int mi = 0; mi < 2; ++mi)
            #pragma unroll
            for (int rg = 0; rg < 4; ++rg) {
                int rowl = wr * 32 + mi * 16 + lg4 * 4 + rg;
                cd[rowl * 4 + wc] = bv[mi * 4 + rg];
            }
    }
    __syncthreads();
    if (tid < 128) {
        double v = fmin(fmin(cd[tid * 4], cd[tid * 4 + 1]),
                        fmin(cd[tid * 4 + 2], cd[tid * 4 + 3]));
        int grow = g0 + tid;
        pv[grow * 2 + ch] = __int_as_float(__double2hiint(v));
        pi[grow * 2 + ch] = __double2loint(v);
    }
}

__global__ __launch_bounds__(256) void k_fin(const float* __restrict__ pv,
                                             const int* __restrict__ pi,
                                             float* __restrict__ out) {
    int t = blockIdx.x * 256 + threadIdx.x;   // row 0..16383
    float v0 = pv[t * 2], v1 = pv[t * 2 + 1];
    int   i0 = pi[t * 2], i1 = pi[t * 2 + 1];
    bool take1 = (v1 < v0) || (v1 == v0 && i1 < i0);
    float v  = take1 ? v1 : v0;
    int   ix = take1 ? i1 : i0;
    out[67108864 + t]         = (float)ix;            // pairs
    out[67108864 + 16384 + t] = v;                    // top_dists
    out[(size_t)t * 4096 + (size_t)ix] = 1.0f;        // one-hot
}

// ================= fallback path (needs only 384 KB ws) =================
__global__ __launch_bounds__(256) void k_rowsq(const float* __restrict__ xd,
                                               const float* __restrict__ yd,
                                               float* __restrict__ ws) {
    int tid  = threadIdx.x;
    int wid  = tid >> 6, lane = tid & 63;
    int gr   = blockIdx.x * 4 + wid;
    const float* src = (gr < 16384) ? (xd + (size_t)gr * 128)
                                    : (yd + (size_t)(gr - 16384) * 128);
    float2 v = reinterpret_cast<const float2*>(src)[lane];
    float s  = v.x * v.x + v.y * v.y;
    for (int off = 32; off > 0; off >>= 1) s += __shfl_down(s, off);
    if (lane == 0) ws[gr] = s;
}

__global__ __launch_bounds__(256, 1) void k_main_fb(const float* __restrict__ xd,
                                                    const float* __restrict__ yd,
                                                    const float* __restrict__ mask,
                                                    const float* __restrict__ ws,
                                                    float* __restrict__ pvals,
                                                    int* __restrict__ pidx,
                                                    float* __restrict__ mm) {
    __shared__ __align__(16) float Xs[128 * 128];
    __shared__ __align__(16) float Ys[128 * 128];
    const int bid  = blockIdx.x;
    const int mh   = bid & 1;
    const int rb   = (bid >> 1) & 31;
    const int b    = bid >> 6;
    const int tid  = threadIdx.x;
    const int ty   = tid >> 4;
    const int tx   = tid & 15;
    const int row0 = rb * 128;
    const int m0   = mh * 2048;
    {
        const float4 z = make_float4(0.f, 0.f, 0.f, 0.f);
        size_t base = ((size_t)(b * 4096 + row0)) * 4096 + (size_t)m0;
        for (int r = 0; r < 128; ++r) {
            float4* p = reinterpret_cast<float4*>(mm + base + (size_t)r * 4096);
            p[tid] = z; p[tid + 256] = z;
        }
    }
    {
        int lrow = tid >> 5, slot = tid & 31;
        for (int p = 0; p < 16; ++p) {
            int row  = p * 8 + lrow;
            float4 v = reinterpret_cast<const float4*>(
                           xd + ((size_t)(b * 4096 + row0 + row)) * 128)[slot];
            int ss = slot ^ (row & 31);
            *reinterpret_cast<float4*>(&Xs[row * 128 + (ss << 2)]) = v;
        }
    }
    float x2r[8];
    #pragma unroll
    for (int i = 0; i < 8; ++i) x2r[i] = ws[b * 4096 + row0 + ty * 8 + i];
    const float* y2g = ws + 16384 + b * 4096;
    float bv[8]; int bi[8];
    #pragma unroll
    for (int i = 0; i < 8; ++i) { bv[i] = 3.4e38f; bi[i] = 0; }
    __syncthreads();
    for (int tile = 0; tile < 16; ++tile) {
        const int mbase = m0 + tile * 128;
        {
            int lrow = tid >> 5, slot = tid & 31;
            for (int p = 0; p < 16; ++p) {
                int row  = p * 8 + lrow;
                float4 v = reinterpret_cast<const float4*>(
                               yd + ((size_t)(b * 4096 + mbase + row)) * 128)[slot];
                int ss = slot ^ (row & 31);
                *reinterpret_cast<float4*>(&Ys[row * 128 + (ss << 2)]) = v;
            }
        }
        __syncthreads();
        float acc[8][8];
        #pragma unroll
        for (int i = 0; i < 8; ++i)
            #pragma unroll
            for (int jj = 0; jj < 8; ++jj) acc[i][jj] = 0.0f;
        #pragma unroll 4
        for (int ks = 0; ks < 32; ++ks) {
            float4 bf[8];
            #pragma unroll
            for (int jj = 0; jj < 8; ++jj) {
                int c = jj * 16 + tx;
                bf[jj] = *reinterpret_cast<const float4*>(&Ys[c * 128 + ((ks ^ (c & 31)) << 2)]);
            }
            #pragma unroll
            for (int i = 0; i < 8; ++i) {
                int r = ty * 8 + i;
                float4 a = *reinterpret_cast<const float4*>(&Xs[r * 128 + ((ks ^ (r & 31)) << 2)]);
                #pragma unroll
                for (int jj = 0; jj < 8; ++jj) {
                    acc[i][jj] = fmaf(a.x, bf[jj].x, acc[i][jj]);
                    acc[i][jj] = fmaf(a.y, bf[jj].y, acc[i][jj]);
                    acc[i][jj] = fmaf(a.z, bf[jj].z, acc[i][jj]);
                    acc[i][jj] = fmaf(a.w, bf[jj].w, acc[i][jj]);
                }
            }
        }
        float y2v[8];
        #pragma unroll
        for (int jj = 0; jj < 8; ++jj) y2v[jj] = y2g[mbase + jj * 16 + tx];
        #pragma unroll
        for (int i = 0; i < 8; ++i) {
            int r = ty * 8 + i;
            const float* mr = mask + ((size_t)(b * 4096 + row0 + r)) * 4096;
            #pragma unroll
            for (int jj = 0; jj < 8; ++jj) {
                int   m  = mbase + jj * 16 + tx;
                float d2 = x2r[i] + y2v[jj] - 2.0f * acc[i][jj];
                float d  = sqrtf(fmaxf(d2, 0.0f)) * mr[m];
                if (d < bv[i]) { bv[i] = d; bi[i] = m; }
            }
        }
        __syncthreads();
    }
    float* candv = Xs;
    int*   candi = reinterpret_cast<int*>(Xs + 2048);
    #pragma unroll
    for (int i = 0; i < 8; ++i) {
        int r = ty * 8 + i;
        candv[r * 16 + tx] = bv[i];
        candi[r * 16 + tx] = bi[i];
    }
    __syncthreads();
    if (tid < 128) {
        int   r  = tid;
        float v  = candv[r * 16];
        int   ix = candi[r * 16];
        for (int t = 1; t < 16; ++t) {
            float v2 = candv[r * 16 + t];
            int   i2 = candi[r * 16 + t];
            if (v2 < v || (v2 == v && i2 < ix)) { v = v2; ix = i2; }
        }
        int grow = b * 4096 + row0 + r;
        pvals[grow * 2 + mh] = v;
        pidx [grow * 2 + mh] = ix;
    }
}

__global__ __launch_bounds__(256) void k_fin_fb(const float* __restrict__ pvals,
                                                const int* __restrict__ pidx,
                                                float* __restrict__ out) {
    int t = blockIdx.x * 256 + threadIdx.x;
    float v0 = pvals[t * 2], v1 = pvals[t * 2 + 1];
    int   i0 = pidx [t * 2], i1 = pidx [t * 2 + 1];
    bool take1 = (v1 < v0) || (v1 == v0 && i1 < i0);
    float v  = take1 ? v1 : v0;
    int   ix = take1 ? i1 : i0;
    out[67108864 + t]         = (float)ix;
    out[67108864 + 16384 + t] = v;
    out[(size_t)t * 4096 + (size_t)ix] = 1.0f;
}

extern "C" void kernel_launch(void* const* d_in, const int* in_sizes, int n_in,
                              void* d_out, int out_size, void* d_ws, size_t ws_size,
                              hipStream_t stream) {
    const float* xd   = (const float*)d_in[0];
    const float* yd   = (const float*)d_in[1];
    const float* mask = (const float*)d_in[2];
    float* out = (float*)d_out;
    float* wsf = (float*)d_ws;

    const size_t need = 131072 + 6 * PS * 2 + 262144;   // 25,559,040
    if (ws_size >= need) {
        unsigned short* pl = (unsigned short*)((char*)d_ws + 131072);
        float* pv = (float*)((char*)d_ws + 131072 + 6 * PS * 2);
        int*   pi = (int*)  ((char*)d_ws + 131072 + 6 * PS * 2 + 131072);
        k_prep <<<2048, 256,  0, stream>>>(xd, yd, pl, wsf);
        k_gemm <<<256,  1024, 0, stream>>>(mask, wsf, pl, out, pv, pi);
        k_fin  <<<64,   256,  0, stream>>>(pv, pi, out);
    } else {
        float* pvals = wsf + 32768;
        int*   pidx  = (int*)(wsf + 65536);
        k_rowsq  <<<8192, 256, 0, stream>>>(xd, yd, wsf);
        k_main_fb<<<256,  256, 0, stream>>>(xd, yd, mask, wsf, pvals, pidx, out);
        k_fin_fb <<<64,   256, 0, stream>>>(pvals, pidx, out);
    }
}

// Round 14
// 184.843 us; speedup vs baseline: 10.9225x; 10.9225x over previous
//
#include <hip/hip_runtime.h>

// B=4, N=M=4096, D=128.
// d_out (floats): match_mask [4*4096*4096] | pairs [16384] (as float) | top_dists [16384]
// ws fast path:
//   bytes [0, 131072):        x2 [16384] f32 | y2 [16384] f32
//   bytes [131072, 25296896): planes, 6 x PS elems bf16 (x:h,m,l then y:h,m,l)
//     32x32-fragment chunk layout: chunk idx (b*2+kh)*128 + t32  (t32 = row>>5), 2048 elems:
//       [kc(4)][lane(64)][e(8)] holding in[b][t32*32 + (lane&31)][kh*64 + kc*16 + (lane>>5)*8 + e]
//   then pv [16384*2] f32 | pi [16384*2] i32
// Products: hh, hm, mh, mm, hl, lh (A-plane x B-plane), via mfma_f32_32x32x16_bf16.
// Round-14: 32x32 MFMA halves LDS-read traffic (the measured dominant pipe).
// A h,m in LDS (64K) + A-l in regs (nt-invariant); B h,m,l double-slot LDS (96K).
// 2-phase/nt lockstep, waits N_A=4 / N_B=38 (position-robust counts).

typedef float  f32x4   __attribute__((ext_vector_type(4)));
typedef float  f32x16  __attribute__((ext_vector_type(16)));
typedef short  bf16x8  __attribute__((ext_vector_type(8)));

#define PS ((size_t)2097152)

#define WAITVM_(N) asm volatile("s_waitcnt vmcnt(" #N ")" ::: "memory")
#define WAITVM(N)  WAITVM_(N)
#define BAR        __builtin_amdgcn_s_barrier()
#define FENCE      asm volatile("" ::: "memory")

__device__ __forceinline__ unsigned short f2bf(float x) {
    unsigned u = __float_as_uint(x);
    u += 0x7FFFu + ((u >> 16) & 1u);
    return (unsigned short)(u >> 16);
}
__device__ __forceinline__ float bf2f(unsigned short s) {
    return __uint_as_float(((unsigned)s) << 16);
}
__device__ __forceinline__ void gload_lds16(const void* g, void* l) {
    __builtin_amdgcn_global_load_lds(
        (const __attribute__((address_space(1))) void*)g,
        (__attribute__((address_space(3))) void*)l, 16, 0, 0);
}

// ---- split f32 -> 3 bf16 planes (32x32 fragment order) + fused row sum-of-squares ----
__global__ __launch_bounds__(256) void k_prep(const float* __restrict__ xd,
                                              const float* __restrict__ yd,
                                              unsigned short* __restrict__ pl,
                                              float* __restrict__ ws) {
    __shared__ float sm[4][16];
    int bid  = blockIdx.x;            // 0..2047
    int i    = bid >> 10;
    int b    = (bid >> 8) & 3;
    int rblk = bid & 255;             // 16-row block
    int tid  = threadIdx.x;
    int kb   = tid >> 6;              // 0..3 (32-k block)
    int l    = tid & 63;
    int lg4  = (l >> 4) & 3;
    int r    = rblk * 16 + (l & 15);
    int k0   = kb * 32 + lg4 * 8;
    const float* src = (i ? yd : xd) + ((size_t)(b * 4096 + r) * 128 + k0);
    float v[8];
    *reinterpret_cast<float4*>(v)     = *reinterpret_cast<const float4*>(src);
    *reinterpret_cast<float4*>(v + 4) = *reinterpret_cast<const float4*>(src + 4);
    bf16x8 hv, mv, lv;
    float s = 0.f;
    #pragma unroll
    for (int e = 0; e < 8; ++e) {
        float x = v[e];
        s = fmaf(x, x, s);
        unsigned short h  = f2bf(x);
        float r1 = x - bf2f(h);
        unsigned short m  = f2bf(r1);
        float r2 = r1 - bf2f(m);
        unsigned short lo = f2bf(r2);
        hv[e] = (short)h; mv[e] = (short)m; lv[e] = (short)lo;
    }
    // new 32x32-fragment destination
    int kh   = kb >> 1;
    int kc2  = (kb & 1) * 2 + (lg4 >> 1);
    int land = (r & 31) + ((lg4 & 1) << 5);
    size_t base = ((size_t)((b * 2 + kh) * 128 + (rblk >> 1))) * 2048
                + (size_t)(kc2 * 64 + land) * 8;
    unsigned short* dst = pl + (size_t)(i * 3) * PS;
    *reinterpret_cast<bf16x8*>(dst + base)          = hv;
    *reinterpret_cast<bf16x8*>(dst + base + PS)     = mv;
    *reinterpret_cast<bf16x8*>(dst + base + 2 * PS) = lv;
    s += __shfl_xor(s, 16);
    s += __shfl_xor(s, 32);
    if (l < 16) sm[kb][l] = s;
    __syncthreads();
    if (tid < 16) {
        float t = sm[0][tid] + sm[1][tid] + sm[2][tid] + sm[3][tid];
        ws[(i ? 16384 : 0) + b * 4096 + rblk * 16 + tid] = t;
    }
}

// ---- main: 32x32 MFMA, A h,m LDS + A-l regs, B h,m,l double-slot LDS ----
__global__ __launch_bounds__(512, 1) void k_gemm(const float* __restrict__ mask,
                                                 const float* __restrict__ ws,
                                                 const unsigned short* __restrict__ pl,
                                                 float* __restrict__ out,
                                                 float* __restrict__ pv,
                                                 int* __restrict__ pi) {
    __shared__ __align__(16) unsigned short Ab[2][2][8192];  // 64 KiB: A h,m per kh
    __shared__ __align__(16) unsigned short Bp[2][3][8192];  // 96 KiB: [slot][plane h,m,l]

    const int bid = blockIdx.x;        // 256 blocks = 1/CU
    const int xcd = bid & 7;
    const int b   = xcd >> 1;          // batch pinned per XCD pair
    const int ch  = xcd & 1;           // col half (2048 cols)
    const int rt  = bid >> 3;          // 128-row tile 0..31
    const int tid = threadIdx.x;
    const int w   = tid >> 6, l = tid & 63;
    const int wr  = w >> 1, wc = w & 1;     // 4x2 waves: 32 rows x 64 cols each
    const int l31 = l & 31, lg1 = l >> 5;
    const int g0  = b * 4096 + rt * 128;

    // x2 for this thread's 16 rows (32x32 C-layout rows)
    float x2r[16];
    #pragma unroll
    for (int rg = 0; rg < 16; ++rg)
        x2r[rg] = ws[g0 + wr * 32 + (rg & 3) + 8 * (rg >> 2) + 4 * lg1];

    const float* y2g = ws + 16384 + b * 4096 + ch * 2048 + wc * 64 + l31;

    // ---- prologue: A h,m -> LDS; A-l -> regs; B nt0 kh0 -> slot0; pm/yv nt0 ----
    #pragma unroll
    for (int kh = 0; kh < 2; ++kh)
        #pragma unroll
        for (int ap = 0; ap < 2; ++ap) {
            const unsigned short* Ac = pl + (size_t)ap * PS
                + (((size_t)((b * 2 + kh) * 128 + rt * 4)) << 11);
            gload_lds16((const char*)Ac + w * 1024 + l * 16,
                        (char*)(&Ab[kh][ap][0]) + w * 1024);
            gload_lds16((const char*)Ac + 8192 + w * 1024 + l * 16,
                        (char*)(&Ab[kh][ap][0]) + 8192 + w * 1024);
        }
    bf16x8 Al[2][4];
    #pragma unroll
    for (int kh = 0; kh < 2; ++kh)
        #pragma unroll
        for (int kc = 0; kc < 4; ++kc)
            Al[kh][kc] = *reinterpret_cast<const bf16x8*>(
                pl + (size_t)2 * PS
                + (((size_t)((b * 2 + kh) * 128 + rt * 4 + wr)) << 11)
                + (size_t)(kc * 64 + l) * 8);

#define STAGE_B(NTT, KH, SLOT) do {                                               \
    _Pragma("unroll") for (int bp_ = 0; bp_ < 3; ++bp_) {                         \
        const unsigned short* Bc_ = pl + (size_t)(3 + bp_) * PS                   \
            + (((size_t)((b * 2 + (KH)) * 128 + ch * 64 + (NTT) * 4)) << 11);     \
        gload_lds16((const char*)Bc_ + w * 1024 + l * 16,                         \
                    (char*)(&Bp[SLOT][bp_][0]) + w * 1024);                       \
        gload_lds16((const char*)Bc_ + 8192 + w * 1024 + l * 16,                  \
                    (char*)(&Bp[SLOT][bp_][0]) + 8192 + w * 1024);                \
    }                                                                             \
} while (0)

#define MLOAD34(NT) do {                                                          \
    _Pragma("unroll") for (int K = 0; K < 32; ++K) {                              \
        const int rg_ = K >> 1, ni_ = K & 1;                                      \
        const int row_ = wr * 32 + (rg_ & 3) + 8 * (rg_ >> 2) + 4 * lg1;          \
        pm[K] = mask[(size_t)(g0 + row_) * 4096                                   \
                     + (ch * 2048 + (NT) * 128 + wc * 64 + ni_ * 32 + l31)];      \
    }                                                                             \
    yv[0] = y2g[(NT) * 128];                                                      \
    yv[1] = y2g[(NT) * 128 + 32];                                                 \
} while (0)

#define ZST(NT, I) do {                                                           \
    const f32x4 z_ = (f32x4){0.f, 0.f, 0.f, 0.f};                                 \
    const int r_ = (tid >> 5) * 8 + (I);                                          \
    *reinterpret_cast<f32x4*>(out + (size_t)(g0 + r_) * 4096                      \
        + ch * 2048 + (NT) * 128 + ((tid & 31) << 2)) = z_;                       \
} while (0)

// per-phase: 4 kc x { A h,m reads; per ni: B h,m,l reads; 6 MFMA } = 48 MFMA(32x32)
#define COMPUTE(KH, SLOT) do {                                                    \
    __builtin_amdgcn_s_setprio(1);                                                \
    _Pragma("unroll") for (int kc = 0; kc < 4; ++kc) {                            \
        const int fa = (((wr * 4 + kc) * 64) + l) * 8;                            \
        bf16x8 Ah_ = *reinterpret_cast<const bf16x8*>(&Ab[KH][0][fa]);            \
        bf16x8 Am_ = *reinterpret_cast<const bf16x8*>(&Ab[KH][1][fa]);            \
        bf16x8 Al_ = Al[KH][kc];                                                  \
        _Pragma("unroll") for (int ni = 0; ni < 2; ++ni) {                        \
            const int fb = ((((wc * 2 + ni) * 4 + kc) * 64) + l) * 8;             \
            bf16x8 Bh_ = *reinterpret_cast<const bf16x8*>(&Bp[SLOT][0][fb]);      \
            bf16x8 Bm_ = *reinterpret_cast<const bf16x8*>(&Bp[SLOT][1][fb]);      \
            bf16x8 Bl_ = *reinterpret_cast<const bf16x8*>(&Bp[SLOT][2][fb]);      \
            f32x16 c_ = acc[ni];                                                  \
            c_ = __builtin_amdgcn_mfma_f32_32x32x16_bf16(Ah_, Bh_, c_, 0, 0, 0);  \
            c_ = __builtin_amdgcn_mfma_f32_32x32x16_bf16(Am_, Bh_, c_, 0, 0, 0);  \
            c_ = __builtin_amdgcn_mfma_f32_32x32x16_bf16(Al_, Bh_, c_, 0, 0, 0);  \
            c_ = __builtin_amdgcn_mfma_f32_32x32x16_bf16(Ah_, Bm_, c_, 0, 0, 0);  \
            c_ = __builtin_amdgcn_mfma_f32_32x32x16_bf16(Am_, Bm_, c_, 0, 0, 0);  \
            c_ = __builtin_amdgcn_mfma_f32_32x32x16_bf16(Ah_, Bl_, c_, 0, 0, 0);  \
            acc[ni] = c_;                                                         \
        }                                                                         \
    }                                                                             \
    __builtin_amdgcn_s_setprio(0);                                                \
} while (0)

    float pm[32], yv[2];
    f32x16 acc[2];

    STAGE_B(0, 0, 0);
    MLOAD34(0);
    WAITVM(0);
    BAR;

    const double INITD = __hiloint2double(0x7f7fffff, 0);
    double bv[16];
    #pragma unroll
    for (int q = 0; q < 16; ++q) bv[q] = INITD;

    #pragma unroll 1
    for (int nt = 0; nt < 16; ++nt) {
        const int ntn = (nt < 15) ? nt + 1 : 15;

        // ---- Phase A: compute kh0 (slot0); stage kh1 -> slot1; masks for nt ----
        WAITVM(4); BAR;                 // retire prev-B stage; leave its 4 ZSTs
        #pragma unroll
        for (int ni = 0; ni < 2; ++ni)
            #pragma unroll
            for (int e = 0; e < 16; ++e) acc[ni][e] = 0.f;
        STAGE_B(nt, 1, 1);
        FENCE;
        if (nt > 0) MLOAD34(nt);        // nt0's loaded in prologue
        ZST(nt, 0); ZST(nt, 1); ZST(nt, 2); ZST(nt, 3);
        COMPUTE(0, 0);

        // ---- Phase B: compute kh1 (slot1); stage next kh0 -> slot0; epilogue ----
        WAITVM(38); BAR;                // retire A's stage; leave pm34+zstA4
        STAGE_B(ntn, 0, 0);
        FENCE;
        ZST(nt, 4); ZST(nt, 5); ZST(nt, 6); ZST(nt, 7);
        COMPUTE(1, 1);

        // epilogue: packed (dist,col) f64 argmin (pm/yv retired by compiler wait)
        #pragma unroll
        for (int ni = 0; ni < 2; ++ni) {
            const int c = ch * 2048 + nt * 128 + wc * 64 + ni * 32 + l31;
            #pragma unroll
            for (int rg = 0; rg < 16; ++rg) {
                float d2 = fmaf(acc[ni][rg], -2.0f, x2r[rg]) + yv[ni];
                float d  = sqrtf(fmaxf(d2, 0.0f)) * pm[rg * 2 + ni];
                double pk = __hiloint2double(__float_as_int(d), c);
                bv[rg] = fmin(bv[rg], pk);
            }
        }
    }
#undef STAGE_B
#undef MLOAD34
#undef ZST
#undef COMPUTE

    WAITVM(0);

    // ---- reduce across 32 col-lanes (packed min), then 2 col-waves via LDS ----
    #pragma unroll
    for (int off = 1; off < 32; off <<= 1) {
        #pragma unroll
        for (int q = 0; q < 16; ++q)
            bv[q] = fmin(bv[q], __shfl_xor(bv[q], off));
    }
    __syncthreads();                    // B LDS free; overlay candidates
    double* cd = reinterpret_cast<double*>(&Bp[0][0][0]);   // [128][2]
    if (l31 == 0) {
        #pragma unroll
        for (int rg = 0; rg < 16; ++rg) {
            int rowl = wr * 32 + (rg & 3) + 8 * (rg >> 2) + 4 * lg1;
            cd[rowl * 2 + wc] = bv[rg];
        }
    }
    __syncthreads();
    if (tid < 128) {
        double v = fmin(cd[tid * 2], cd[tid * 2 + 1]);
        int grow = g0 + tid;
        pv[grow * 2 + ch] = __int_as_float(__double2hiint(v));
        pi[grow * 2 + ch] = __double2loint(v);
    }
}

__global__ __launch_bounds__(256) void k_fin(const float* __restrict__ pv,
                                             const int* __restrict__ pi,
                                             float* __restrict__ out) {
    int t = blockIdx.x * 256 + threadIdx.x;   // row 0..16383
    float v0 = pv[t * 2], v1 = pv[t * 2 + 1];
    int   i0 = pi[t * 2], i1 = pi[t * 2 + 1];
    bool take1 = (v1 < v0) || (v1 == v0 && i1 < i0);
    float v  = take1 ? v1 : v0;
    int   ix = take1 ? i1 : i0;
    out[67108864 + t]         = (float)ix;            // pairs
    out[67108864 + 16384 + t] = v;                    // top_dists
    out[(size_t)t * 4096 + (size_t)ix] = 1.0f;        // one-hot
}

// ================= fallback path (needs only 384 KB ws) =================
__global__ __launch_bounds__(256) void k_rowsq(const float* __restrict__ xd,
                                               const float* __restrict__ yd,
                                               float* __restrict__ ws) {
    int tid  = threadIdx.x;
    int wid  = tid >> 6, lane = tid & 63;
    int gr   = blockIdx.x * 4 + wid;
    const float* src = (gr < 16384) ? (xd + (size_t)gr * 128)
                                    : (yd + (size_t)(gr - 16384) * 128);
    float2 v = reinterpret_cast<const float2*>(src)[lane];
    float s  = v.x * v.x + v.y * v.y;
    for (int off = 32; off > 0; off >>= 1) s += __shfl_down(s, off);
    if (lane == 0) ws[gr] = s;
}

__global__ __launch_bounds__(256, 1) void k_main_fb(const float* __restrict__ xd,
                                                    const float* __restrict__ yd,
                                                    const float* __restrict__ mask,
                                                    const float* __restrict__ ws,
                                                    float* __restrict__ pvals,
                                                    int* __restrict__ pidx,
                                                    float* __restrict__ mm) {
    __shared__ __align__(16) float Xs[128 * 128];
    __shared__ __align__(16) float Ys[128 * 128];
    const int bid  = blockIdx.x;
    const int mh   = bid & 1;
    const int rb   = (bid >> 1) & 31;
    const int b    = bid >> 6;
    const int tid  = threadIdx.x;
    const int ty   = tid >> 4;
    const int tx   = tid & 15;
    const int row0 = rb * 128;
    const int m0   = mh * 2048;
    {
        const float4 z = make_float4(0.f, 0.f, 0.f, 0.f);
        size_t base = ((size_t)(b * 4096 + row0)) * 4096 + (size_t)m0;
        for (int r = 0; r < 128; ++r) {
            float4* p = reinterpret_cast<float4*>(mm + base + (size_t)r * 4096);
            p[tid] = z; p[tid + 256] = z;
        }
    }
    {
        int lrow = tid >> 5, slot = tid & 31;
        for (int p = 0; p < 16; ++p) {
            int row  = p * 8 + lrow;
            float4 v = reinterpret_cast<const float4*>(
                           xd + ((size_t)(b * 4096 + row0 + row)) * 128)[slot];
            int ss = slot ^ (row & 31);
            *reinterpret_cast<float4*>(&Xs[row * 128 + (ss << 2)]) = v;
        }
    }
    float x2r[8];
    #pragma unroll
    for (int i = 0; i < 8; ++i) x2r[i] = ws[b * 4096 + row0 + ty * 8 + i];
    const float* y2g = ws + 16384 + b * 4096;
    float bv[8]; int bi[8];
    #pragma unroll
    for (int i = 0; i < 8; ++i) { bv[i] = 3.4e38f; bi[i] = 0; }
    __syncthreads();
    for (int tile = 0; tile < 16; ++tile) {
        const int mbase = m0 + tile * 128;
        {
            int lrow = tid >> 5, slot = tid & 31;
            for (int p = 0; p < 16; ++p) {
                int row  = p * 8 + lrow;
                float4 v = reinterpret_cast<const float4*>(
                               yd + ((size_t)(b * 4096 + mbase + row)) * 128)[slot];
                int ss = slot ^ (row & 31);
                *reinterpret_cast<float4*>(&Ys[row * 128 + (ss << 2)]) = v;
            }
        }
        __syncthreads();
        float acc[8][8];
        #pragma unroll
        for (int i = 0; i < 8; ++i)
            #pragma unroll
            for (int jj = 0; jj < 8; ++jj) acc[i][jj] = 0.0f;
        #pragma unroll 4
        for (int ks = 0; ks < 32; ++ks) {
            float4 bf[8];
            #pragma unroll
            for (int jj = 0; jj < 8; ++jj) {
                int c = jj * 16 + tx;
                bf[jj] = *reinterpret_cast<const float4*>(&Ys[c * 128 + ((ks ^ (c & 31)) << 2)]);
            }
            #pragma unroll
            for (int i = 0; i < 8; ++i) {
                int r = ty * 8 + i;
                float4 a = *reinterpret_cast<const float4*>(&Xs[r * 128 + ((ks ^ (r & 31)) << 2)]);
                #pragma unroll
                for (int jj = 0; jj < 8; ++jj) {
                    acc[i][jj] = fmaf(a.x, bf[jj].x, acc[i][jj]);
                    acc[i][jj] = fmaf(a.y, bf[jj].y, acc[i][jj]);
                    acc[i][jj] = fmaf(a.z, bf[jj].z, acc[i][jj]);
                    acc[i][jj] = fmaf(a.w, bf[jj].w, acc[i][jj]);
                }
            }
        }
        float y2v[8];
        #pragma unroll
        for (int jj = 0; jj < 8; ++jj) y2v[jj] = y2g[mbase + jj * 16 + tx];
        #pragma unroll
        for (int i = 0; i < 8; ++i) {
            int r = ty * 8 + i;
            const float* mr = mask + ((size_t)(b * 4096 + row0 + r)) * 4096;
            #pragma unroll
            for (int jj = 0; jj < 8; ++jj) {
                int   m  = mbase + jj * 16 + tx;
                float d2 = x2r[i] + y2v[jj] - 2.0f * acc[i][jj];
                float d  = sqrtf(fmaxf(d2, 0.0f)) * mr[m];
                if (d < bv[i]) { bv[i] = d; bi[i] = m; }
            }
        }
        __syncthreads();
    }
    float* candv = Xs;
    int*   candi = reinterpret_cast<int*>(Xs + 2048);
    #pragma unroll
    for (int i = 0; i < 8; ++i) {
        int r = ty * 8 + i;
        candv[r * 16 + tx] = bv[i];
        candi[r * 16 + tx] = bi[i];
    }
    __syncthreads();
    if (tid < 128) {
        int   r  = tid;
        float v  = candv[r * 16];
        int   ix = candi[r * 16];
        for (int t = 1; t < 16; ++t) {
            float v2 = candv[r * 16 + t];
            int   i2 = candi[r * 16 + t];
            if (v2 < v || (v2 == v && i2 < ix)) { v = v2; ix = i2; }
        }
        int grow = b * 4096 + row0 + r;
        pvals[grow * 2 + mh] = v;
        pidx [grow * 2 + mh] = ix;
    }
}

__global__ __launch_bounds__(256) void k_fin_fb(const float* __restrict__ pvals,
                                                const int* __restrict__ pidx,
                                                float* __restrict__ out) {
    int t = blockIdx.x * 256 + threadIdx.x;
    float v0 = pvals[t * 2], v1 = pvals[t * 2 + 1];
    int   i0 = pidx [t * 2], i1 = pidx [t * 2 + 1];
    bool take1 = (v1 < v0) || (v1 == v0 && i1 < i0);
    float v  = take1 ? v1 : v0;
    int   ix = take1 ? i1 : i0;
    out[67108864 + t]         = (float)ix;
    out[67108864 + 16384 + t] = v;
    out[(size_t)t * 4096 + (size_t)ix] = 1.0f;
}

extern "C" void kernel_launch(void* const* d_in, const int* in_sizes, int n_in,
                              void* d_out, int out_size, void* d_ws, size_t ws_size,
                              hipStream_t stream) {
    const float* xd   = (const float*)d_in[0];
    const float* yd   = (const float*)d_in[1];
    const float* mask = (const float*)d_in[2];
    float* out = (float*)d_out;
    float* wsf = (float*)d_ws;

    const size_t need = 131072 + 6 * PS * 2 + 262144;   // 25,559,040
    if (ws_size >= need) {
        unsigned short* pl = (unsigned short*)((char*)d_ws + 131072);
        float* pv = (float*)((char*)d_ws + 131072 + 6 * PS * 2);
        int*   pi = (int*)  ((char*)d_ws + 131072 + 6 * PS * 2 + 131072);
        k_prep <<<2048, 256, 0, stream>>>(xd, yd, pl, wsf);
        k_gemm <<<256,  512, 0, stream>>>(mask, wsf, pl, out, pv, pi);
        k_fin  <<<64,   256, 0, stream>>>(pv, pi, out);
    } else {
        float* pvals = wsf + 32768;
        int*   pidx  = (int*)(wsf + 65536);
        k_rowsq  <<<8192, 256, 0, stream>>>(xd, yd, wsf);
        k_main_fb<<<256,  256, 0, stream>>>(xd, yd, mask, wsf, pvals, pidx, out);
        k_fin_fb <<<64,   256, 0, stream>>>(pvals, pidx, out);
    }
}

// Round 15
// 178.990 us; speedup vs baseline: 11.2797x; 1.0327x over previous
//
#include <hip/hip_runtime.h>

// B=4, N=M=4096, D=128.
// d_out (floats): match_mask [4*4096*4096] | pairs [16384] (as float) | top_dists [16384]
// ws fast path:
//   bytes [0, 131072):        x2 [16384] f32 | y2 [16384] f32
//   bytes [131072, 25296896): planes, 6 x PS elems bf16 (x:h,m,l then y:h,m,l)
//     32x32-fragment chunks: chunk idx (b*2+kh)*128 + t32 (t32=row>>5), 2048 elems (4KB):
//       [kc(4)][lane(64)][e(8)] holding in[b][t32*32+(lane&31)][kh*64+kc*16+(lane>>5)*8+e]
//   then pv [16384*2] f32 | pi [16384*2] i32
// Products: hh, hm, mh, mm, hl, lh via mfma_f32_32x32x16_bf16.
// Round-15: 2 blocks/CU (80 KiB LDS each) for cross-block barrier-slack hiding.
// 64-row x 2048-col blocks, 256 thr (2x2 waves of 32x32), phase=(kh, 64 cols).
// Waits WAITVM(2)/WAITVM(18) (invariant-checked); stores never force-drained.

typedef float  f32x4   __attribute__((ext_vector_type(4)));
typedef float  f32x16  __attribute__((ext_vector_type(16)));
typedef short  bf16x8  __attribute__((ext_vector_type(8)));

#define PS ((size_t)2097152)

#define WAITVM_(N) asm volatile("s_waitcnt vmcnt(" #N ")" ::: "memory")
#define WAITVM(N)  WAITVM_(N)
#define BAR        __builtin_amdgcn_s_barrier()
#define FENCE      asm volatile("" ::: "memory")

__device__ __forceinline__ unsigned short f2bf(float x) {
    unsigned u = __float_as_uint(x);
    u += 0x7FFFu + ((u >> 16) & 1u);
    return (unsigned short)(u >> 16);
}
__device__ __forceinline__ float bf2f(unsigned short s) {
    return __uint_as_float(((unsigned)s) << 16);
}
__device__ __forceinline__ void gload_lds16(const void* g, void* l) {
    __builtin_amdgcn_global_load_lds(
        (const __attribute__((address_space(1))) void*)g,
        (__attribute__((address_space(3))) void*)l, 16, 0, 0);
}

// ---- split f32 -> 3 bf16 planes (32x32 fragment order) + fused row sum-of-squares ----
__global__ __launch_bounds__(256) void k_prep(const float* __restrict__ xd,
                                              const float* __restrict__ yd,
                                              unsigned short* __restrict__ pl,
                                              float* __restrict__ ws) {
    __shared__ float sm[4][16];
    int bid  = blockIdx.x;            // 0..2047
    int i    = bid >> 10;
    int b    = (bid >> 8) & 3;
    int rblk = bid & 255;             // 16-row block
    int tid  = threadIdx.x;
    int kb   = tid >> 6;              // 0..3 (32-k block)
    int l    = tid & 63;
    int lg4  = (l >> 4) & 3;
    int r    = rblk * 16 + (l & 15);
    int k0   = kb * 32 + lg4 * 8;
    const float* src = (i ? yd : xd) + ((size_t)(b * 4096 + r) * 128 + k0);
    float v[8];
    *reinterpret_cast<float4*>(v)     = *reinterpret_cast<const float4*>(src);
    *reinterpret_cast<float4*>(v + 4) = *reinterpret_cast<const float4*>(src + 4);
    bf16x8 hv, mv, lv;
    float s = 0.f;
    #pragma unroll
    for (int e = 0; e < 8; ++e) {
        float x = v[e];
        s = fmaf(x, x, s);
        unsigned short h  = f2bf(x);
        float r1 = x - bf2f(h);
        unsigned short m  = f2bf(r1);
        float r2 = r1 - bf2f(m);
        unsigned short lo = f2bf(r2);
        hv[e] = (short)h; mv[e] = (short)m; lv[e] = (short)lo;
    }
    int kh   = kb >> 1;
    int kc2  = (kb & 1) * 2 + (lg4 >> 1);
    int land = (r & 31) + ((lg4 & 1) << 5);
    size_t base = ((size_t)((b * 2 + kh) * 128 + (rblk >> 1))) * 2048
                + (size_t)(kc2 * 64 + land) * 8;
    unsigned short* dst = pl + (size_t)(i * 3) * PS;
    *reinterpret_cast<bf16x8*>(dst + base)          = hv;
    *reinterpret_cast<bf16x8*>(dst + base + PS)     = mv;
    *reinterpret_cast<bf16x8*>(dst + base + 2 * PS) = lv;
    s += __shfl_xor(s, 16);
    s += __shfl_xor(s, 32);
    if (l < 16) sm[kb][l] = s;
    __syncthreads();
    if (tid < 16) {
        float t = sm[0][tid] + sm[1][tid] + sm[2][tid] + sm[3][tid];
        ws[(i ? 16384 : 0) + b * 4096 + rblk * 16 + tid] = t;
    }
}

// ---- main: 64-row blocks, 2/CU, 32x32 MFMA, 2-phase/ct counted-wait pipeline ----
__global__ __launch_bounds__(256, 2) void k_gemm(const float* __restrict__ mask,
                                                 const float* __restrict__ ws,
                                                 const unsigned short* __restrict__ pl,
                                                 float* __restrict__ out,
                                                 float* __restrict__ pv,
                                                 int* __restrict__ pi) {
    __shared__ __align__(16) unsigned short Ab[2][2][4096];  // 32 KiB: A h,m per kh (64 rows)
    __shared__ __align__(16) unsigned short Bp[2][3][4096];  // 48 KiB: [slot][plane h,m,l]

    const int bid = blockIdx.x;        // 512 blocks = 2/CU
    const int xcd = bid & 7;
    const int b   = xcd >> 1;          // batch pinned per XCD pair
    const int ch  = xcd & 1;           // col half (2048 cols)
    const int rt  = bid >> 3;          // 64-row tile 0..63
    const int tid = threadIdx.x;
    const int w   = tid >> 6, l = tid & 63;
    const int wr  = w >> 1, wc = w & 1;     // 2x2 waves: 32 rows x 32 cols per col-step
    const int l31 = l & 31, lg1 = l >> 5;
    const int g0  = b * 4096 + rt * 64;

    float x2r[16];
    #pragma unroll
    for (int rg = 0; rg < 16; ++rg)
        x2r[rg] = ws[g0 + wr * 32 + (rg & 3) + 8 * (rg >> 2) + 4 * lg1];

    const float* y2g = ws + 16384 + b * 4096 + ch * 2048 + wc * 32 + l31;

    // ---- prologue: A h,m -> LDS (8KB per (pl,kh)); A-l -> regs; B ct0,kh0 -> slot0 ----
    #pragma unroll
    for (int kh = 0; kh < 2; ++kh)
        #pragma unroll
        for (int ap = 0; ap < 2; ++ap) {
            const unsigned short* Ac = pl + (size_t)ap * PS
                + (((size_t)((b * 2 + kh) * 128 + rt * 2)) << 11);
            gload_lds16((const char*)Ac + tid * 16,
                        (char*)(&Ab[kh][ap][0]) + tid * 16);
            gload_lds16((const char*)Ac + 4096 + tid * 16,
                        (char*)(&Ab[kh][ap][0]) + 4096 + tid * 16);
        }
    bf16x8 Al[2][4];
    #pragma unroll
    for (int kh = 0; kh < 2; ++kh) {
        const unsigned short* Ac = pl + (size_t)2 * PS
            + (((size_t)((b * 2 + kh) * 128 + rt * 2 + wr)) << 11);
        #pragma unroll
        for (int kc = 0; kc < 4; ++kc)
            Al[kh][kc] = *reinterpret_cast<const bf16x8*>(Ac + (kc * 64 + l) * 8);
    }

#define STAGE_B(CT, KH, SLOT) do {                                                \
    _Pragma("unroll") for (int bp_ = 0; bp_ < 3; ++bp_) {                         \
        const unsigned short* Bc_ = pl + (size_t)(3 + bp_) * PS                   \
            + (((size_t)((b * 2 + (KH)) * 128 + ch * 64 + (CT) * 2)) << 11);      \
        gload_lds16((const char*)Bc_ + tid * 16,                                  \
                    (char*)(&Bp[SLOT][bp_][0]) + tid * 16);                       \
        gload_lds16((const char*)Bc_ + 4096 + tid * 16,                           \
                    (char*)(&Bp[SLOT][bp_][0]) + 4096 + tid * 16);                \
    }                                                                             \
} while (0)

#define MLOAD16(CT) do {                                                          \
    _Pragma("unroll") for (int K = 0; K < 16; ++K) {                              \
        const int row_ = wr * 32 + (K & 3) + 8 * (K >> 2) + 4 * lg1;              \
        pm[K] = mask[(size_t)(g0 + row_) * 4096                                   \
                     + (ch * 2048 + (CT) * 64 + wc * 32 + l31)];                  \
    }                                                                             \
    yv = y2g[(CT) * 64];                                                          \
} while (0)

#define ZST(CT, I) do {                                                           \
    const f32x4 z_ = (f32x4){0.f, 0.f, 0.f, 0.f};                                 \
    *reinterpret_cast<f32x4*>(out + (size_t)(g0 + (I) * 16 + (tid >> 4)) * 4096   \
        + ch * 2048 + (CT) * 64 + ((tid & 15) << 2)) = z_;                        \
} while (0)

// per-phase: 4 kc x { A h,m ds_reads + A-l reg; B h,m,l ds_reads; 6 MFMA } = 24 MFMA
#define COMPUTE(KH, SLOT) do {                                                    \
    __builtin_amdgcn_s_setprio(1);                                                \
    _Pragma("unroll") for (int kc = 0; kc < 4; ++kc) {                            \
        const int fa = wr * 2048 + kc * 512 + l * 8;                              \
        bf16x8 Ah_ = *reinterpret_cast<const bf16x8*>(&Ab[KH][0][fa]);            \
        bf16x8 Am_ = *reinterpret_cast<const bf16x8*>(&Ab[KH][1][fa]);            \
        bf16x8 Al_ = Al[KH][kc];                                                  \
        const int fb = wc * 2048 + kc * 512 + l * 8;                              \
        bf16x8 Bh_ = *reinterpret_cast<const bf16x8*>(&Bp[SLOT][0][fb]);          \
        bf16x8 Bm_ = *reinterpret_cast<const bf16x8*>(&Bp[SLOT][1][fb]);          \
        bf16x8 Bl_ = *reinterpret_cast<const bf16x8*>(&Bp[SLOT][2][fb]);          \
        acc = __builtin_amdgcn_mfma_f32_32x32x16_bf16(Ah_, Bh_, acc, 0, 0, 0);    \
        acc = __builtin_amdgcn_mfma_f32_32x32x16_bf16(Am_, Bh_, acc, 0, 0, 0);    \
        acc = __builtin_amdgcn_mfma_f32_32x32x16_bf16(Al_, Bh_, acc, 0, 0, 0);    \
        acc = __builtin_amdgcn_mfma_f32_32x32x16_bf16(Ah_, Bm_, acc, 0, 0, 0);    \
        acc = __builtin_amdgcn_mfma_f32_32x32x16_bf16(Am_, Bm_, acc, 0, 0, 0);    \
        acc = __builtin_amdgcn_mfma_f32_32x32x16_bf16(Ah_, Bl_, acc, 0, 0, 0);    \
    }                                                                             \
    __builtin_amdgcn_s_setprio(0);                                                \
} while (0)

    float pm[16], yv;
    f32x16 acc;

    STAGE_B(0, 0, 0);
    WAITVM(0);
    BAR;

    const double INITD = __hiloint2double(0x7f7fffff, 0);
    double bv[16];
    #pragma unroll
    for (int q = 0; q < 16; ++q) bv[q] = INITD;

    #pragma unroll 1
    for (int ct = 0; ct < 32; ++ct) {
        const int ctn = (ct < 31) ? ct + 1 : 31;

        // ---- phase kh0: compute slot0; stage kh1 -> slot1; masks for ct ----
        WAITVM(2); BAR;                 // retire stage(s0); leave prev 2 ZSTs
        #pragma unroll
        for (int e = 0; e < 16; ++e) acc[e] = 0.f;
        STAGE_B(ct, 1, 1);
        FENCE;
        MLOAD16(ct);
        FENCE;
        ZST(ct, 0); ZST(ct, 1);
        COMPUTE(0, 0);

        // ---- phase kh1: compute slot1; stage next kh0 -> slot0; epilogue ----
        WAITVM(18); BAR;                // retire stage(s1); leave pm16+zst2
        STAGE_B(ctn, 0, 0);
        FENCE;
        ZST(ct, 2); ZST(ct, 3);
        COMPUTE(1, 1);

        // epilogue: packed (dist,col) f64 argmin (pm/yv via compiler auto-wait)
        {
            const int c = ch * 2048 + ct * 64 + wc * 32 + l31;
            #pragma unroll
            for (int rg = 0; rg < 16; ++rg) {
                float d2 = fmaf(acc[rg], -2.0f, x2r[rg]) + yv;
                float d  = sqrtf(fmaxf(d2, 0.0f)) * pm[rg];
                double pk = __hiloint2double(__float_as_int(d), c);
                bv[rg] = fmin(bv[rg], pk);
            }
        }
    }
#undef STAGE_B
#undef MLOAD16
#undef ZST
#undef COMPUTE

    WAITVM(0);

    // ---- reduce across 32 col-lanes (packed min), then 2 col-waves via LDS ----
    #pragma unroll
    for (int off = 1; off < 32; off <<= 1) {
        #pragma unroll
        for (int q = 0; q < 16; ++q)
            bv[q] = fmin(bv[q], __shfl_xor(bv[q], off));
    }
    __syncthreads();                    // B LDS free; overlay candidates
    double* cd = reinterpret_cast<double*>(&Bp[0][0][0]);   // [64][2]
    if (l31 == 0) {
        #pragma unroll
        for (int rg = 0; rg < 16; ++rg) {
            int rowl = wr * 32 + (rg & 3) + 8 * (rg >> 2) + 4 * lg1;
            cd[rowl * 2 + wc] = bv[rg];
        }
    }
    __syncthreads();
    if (tid < 64) {
        double v = fmin(cd[tid * 2], cd[tid * 2 + 1]);
        int grow = g0 + tid;
        pv[grow * 2 + ch] = __int_as_float(__double2hiint(v));
        pi[grow * 2 + ch] = __double2loint(v);
    }
}

__global__ __launch_bounds__(256) void k_fin(const float* __restrict__ pv,
                                             const int* __restrict__ pi,
                                             float* __restrict__ out) {
    int t = blockIdx.x * 256 + threadIdx.x;   // row 0..16383
    float v0 = pv[t * 2], v1 = pv[t * 2 + 1];
    int   i0 = pi[t * 2], i1 = pi[t * 2 + 1];
    bool take1 = (v1 < v0) || (v1 == v0 && i1 < i0);
    float v  = take1 ? v1 : v0;
    int   ix = take1 ? i1 : i0;
    out[67108864 + t]         = (float)ix;            // pairs
    out[67108864 + 16384 + t] = v;                    // top_dists
    out[(size_t)t * 4096 + (size_t)ix] = 1.0f;        // one-hot
}

// ================= fallback path (needs only 384 KB ws) =================
__global__ __launch_bounds__(256) void k_rowsq(const float* __restrict__ xd,
                                               const float* __restrict__ yd,
                                               float* __restrict__ ws) {
    int tid  = threadIdx.x;
    int wid  = tid >> 6, lane = tid & 63;
    int gr   = blockIdx.x * 4 + wid;
    const float* src = (gr < 16384) ? (xd + (size_t)gr * 128)
                                    : (yd + (size_t)(gr - 16384) * 128);
    float2 v = reinterpret_cast<const float2*>(src)[lane];
    float s  = v.x * v.x + v.y * v.y;
    for (int off = 32; off > 0; off >>= 1) s += __shfl_down(s, off);
    if (lane == 0) ws[gr] = s;
}

__global__ __launch_bounds__(256, 1) void k_main_fb(const float* __restrict__ xd,
                                                    const float* __restrict__ yd,
                                                    const float* __restrict__ mask,
                                                    const float* __restrict__ ws,
                                                    float* __restrict__ pvals,
                                                    int* __restrict__ pidx,
                                                    float* __restrict__ mm) {
    __shared__ __align__(16) float Xs[128 * 128];
    __shared__ __align__(16) float Ys[128 * 128];
    const int bid  = blockIdx.x;
    const int mh   = bid & 1;
    const int rb   = (bid >> 1) & 31;
    const int b    = bid >> 6;
    const int tid  = threadIdx.x;
    const int ty   = tid >> 4;
    const int tx   = tid & 15;
    const int row0 = rb * 128;
    const int m0   = mh * 2048;
    {
        const float4 z = make_float4(0.f, 0.f, 0.f, 0.f);
        size_t base = ((size_t)(b * 4096 + row0)) * 4096 + (size_t)m0;
        for (int r = 0; r < 128; ++r) {
            float4* p = reinterpret_cast<float4*>(mm + base + (size_t)r * 4096);
            p[tid] = z; p[tid + 256] = z;
        }
    }
    {
        int lrow = tid >> 5, slot = tid & 31;
        for (int p = 0; p < 16; ++p) {
            int row  = p * 8 + lrow;
            float4 v = reinterpret_cast<const float4*>(
                           xd + ((size_t)(b * 4096 + row0 + row)) * 128)[slot];
            int ss = slot ^ (row & 31);
            *reinterpret_cast<float4*>(&Xs[row * 128 + (ss << 2)]) = v;
        }
    }
    float x2r[8];
    #pragma unroll
    for (int i = 0; i < 8; ++i) x2r[i] = ws[b * 4096 + row0 + ty * 8 + i];
    const float* y2g = ws + 16384 + b * 4096;
    float bv[8]; int bi[8];
    #pragma unroll
    for (int i = 0; i < 8; ++i) { bv[i] = 3.4e38f; bi[i] = 0; }
    __syncthreads();
    for (int tile = 0; tile < 16; ++tile) {
        const int mbase = m0 + tile * 128;
        {
            int lrow = tid >> 5, slot = tid & 31;
            for (int p = 0; p < 16; ++p) {
                int row  = p * 8 + lrow;
                float4 v = reinterpret_cast<const float4*>(
                               yd + ((size_t)(b * 4096 + mbase + row)) * 128)[slot];
                int ss = slot ^ (row & 31);
                *reinterpret_cast<float4*>(&Ys[row * 128 + (ss << 2)]) = v;
            }
        }
        __syncthreads();
        float acc[8][8];
        #pragma unroll
        for (int i = 0; i < 8; ++i)
            #pragma unroll
            for (int jj = 0; jj < 8; ++jj) acc[i][jj] = 0.0f;
        #pragma unroll 4
        for (int ks = 0; ks < 32; ++ks) {
            float4 bf[8];
            #pragma unroll
            for (int jj = 0; jj < 8; ++jj) {
                int c = jj * 16 + tx;
                bf[jj] = *reinterpret_cast<const float4*>(&Ys[c * 128 + ((ks ^ (c & 31)) << 2)]);
            }
            #pragma unroll
            for (int i = 0; i < 8; ++i) {
                int r = ty * 8 + i;
                float4 a = *reinterpret_cast<const float4*>(&Xs[r * 128 + ((ks ^ (r & 31)) << 2)]);
                #pragma unroll
                for (int jj = 0; jj < 8; ++jj) {
                    acc[i][jj] = fmaf(a.x, bf[jj].x, acc[i][jj]);
                    acc[i][jj] = fmaf(a.y, bf[jj].y, acc[i][jj]);
                    acc[i][jj] = fmaf(a.z, bf[jj].z, acc[i][jj]);
                    acc[i][jj] = fmaf(a.w, bf[jj].w, acc[i][jj]);
                }
            }
        }
        float y2v[8];
        #pragma unroll
        for (int jj = 0; jj < 8; ++jj) y2v[jj] = y2g[mbase + jj * 16 + tx];
        #pragma unroll
        for (int i = 0; i < 8; ++i) {
            int r = ty * 8 + i;
            const float* mr = mask + ((size_t)(b * 4096 + row0 + r)) * 4096;
            #pragma unroll
            for (int jj = 0; jj < 8; ++jj) {
                int   m  = mbase + jj * 16 + tx;
                float d2 = x2r[i] + y2v[jj] - 2.0f * acc[i][jj];
                float d  = sqrtf(fmaxf(d2, 0.0f)) * mr[m];
                if (d < bv[i]) { bv[i] = d; bi[i] = m; }
            }
        }
        __syncthreads();
    }
    float* candv = Xs;
    int*   candi = reinterpret_cast<int*>(Xs + 2048);
    #pragma unroll
    for (int i = 0; i < 8; ++i) {
        int r = ty * 8 + i;
        candv[r * 16 + tx] = bv[i];
        candi[r * 16 + tx] = bi[i];
    }
    __syncthreads();
    if (tid < 128) {
        int   r  = tid;
        float v  = candv[r * 16];
        int   ix = candi[r * 16];
        for (int t = 1; t < 16; ++t) {
            float v2 = candv[r * 16 + t];
            int   i2 = candi[r * 16 + t];
            if (v2 < v || (v2 == v && i2 < ix)) { v = v2; ix = i2; }
        }
        int grow = b * 4096 + row0 + r;
        pvals[grow * 2 + mh] = v;
        pidx [grow * 2 + mh] = ix;
    }
}

__global__ __launch_bounds__(256) void k_fin_fb(const float* __restrict__ pvals,
                                                const int* __restrict__ pidx,
                                                float* __restrict__ out) {
    int t = blockIdx.x * 256 + threadIdx.x;
    float v0 = pvals[t * 2], v1 = pvals[t * 2 + 1];
    int   i0 = pidx [t * 2], i1 = pidx [t * 2 + 1];
    bool take1 = (v1 < v0) || (v1 == v0 && i1 < i0);
    float v  = take1 ? v1 : v0;
    int   ix = take1 ? i1 : i0;
    out[67108864 + t]         = (float)ix;
    out[67108864 + 16384 + t] = v;
    out[(size_t)t * 4096 + (size_t)ix] = 1.0f;
}

extern "C" void kernel_launch(void* const* d_in, const int* in_sizes, int n_in,
                              void* d_out, int out_size, void* d_ws, size_t ws_size,
                              hipStream_t stream) {
    const float* xd   = (const float*)d_in[0];
    const float* yd   = (const float*)d_in[1];
    const float* mask = (const float*)d_in[2];
    float* out = (float*)d_out;
    float* wsf = (float*)d_ws;

    const size_t need = 131072 + 6 * PS * 2 + 262144;   // 25,559,040
    if (ws_size >= need) {
        unsigned short* pl = (unsigned short*)((char*)d_ws + 131072);
        float* pv = (float*)((char*)d_ws + 131072 + 6 * PS * 2);
        int*   pi = (int*)  ((char*)d_ws + 131072 + 6 * PS * 2 + 131072);
        k_prep <<<2048, 256, 0, stream>>>(xd, yd, pl, wsf);
        k_gemm <<<512,  256, 0, stream>>>(mask, wsf, pl, out, pv, pi);
        k_fin  <<<64,   256, 0, stream>>>(pv, pi, out);
    } else {
        float* pvals = wsf + 32768;
        int*   pidx  = (int*)(wsf + 65536);
        k_rowsq  <<<8192, 256, 0, stream>>>(xd, yd, wsf);
        k_main_fb<<<256,  256, 0, stream>>>(xd, yd, mask, wsf, pvals, pidx, out);
        k_fin_fb <<<64,   256, 0, stream>>>(pvals, pidx, out);
    }
}